// Round 3
// baseline (209.123 us; speedup 1.0000x reference)
//
#include <hip/hip_runtime.h>

// 2D CDF 5/3 lifting wavelet, fused. Input x: (24,1024,1024) fp32.
// Output: (8,12,512,512) fp32, planes LL(0..2) LH(3..5) HL(6..8) HH(9..11).
//
// v5: NO LDS, NO BARRIERS. v2/v3/v4 all landed at 60-65us across occupancy
// 37-72% -> the load-convoy/barrier/LDS-phase pipeline is the limiter, not
// occupancy or BW. Here each thread owns one half-res output row r x 4 cols
// and computes the whole 2D transform from global memory directly:
//   - 8 full-res rows (5 even -> SE/DE, 3 odd -> SO/DO), 16-float window each
//   - horizontal lifting recomputed per row in registers (VALU is 11% busy,
//     ~8x headroom; redundancy is free)
//   - 32 independent float4 loads/thread, L1-served (block footprint ~23KB
//     fits 32KB L1; HBM fetch stays ~input-sized)
//   - vertical lifting + 4 float4 stores, zero cross-thread communication.
// This is pure streaming with deep MLP -- the regime where fillBuffer hits
// 6.7 TB/s on this chip.

static __device__ __forceinline__ int mref(int k) {
    // _rpad reflect in half-res index space (N=512): e[-1]->E[1], e[512]->E[510]
    return k < 0 ? 1 : (k > 511 ? 510 : k);
}

static __device__ __forceinline__ float4 lift_sub(float4 o, float4 em, float4 ep) {
    // o - 0.5*(em+ep)
    float4 r;
    r.x = o.x - 0.5f * (em.x + ep.x);
    r.y = o.y - 0.5f * (em.y + ep.y);
    r.z = o.z - 0.5f * (em.z + ep.z);
    r.w = o.w - 0.5f * (em.w + ep.w);
    return r;
}

static __device__ __forceinline__ float4 lift_add(float4 e, float4 dm, float4 dp) {
    // e + 0.25*(dm+dp)
    float4 r;
    r.x = e.x + 0.25f * (dm.x + dp.x);
    r.y = e.y + 0.25f * (dm.y + dp.y);
    r.z = e.z + 0.25f * (dm.z + dp.z);
    r.w = e.w + 0.25f * (dm.w + dp.w);
    return r;
}

// Horizontal lifting for half-res cols c..c+3 of one full-res row (c mult of 4).
// s4 = smooth (s_row) cols c..c+3, d4 = detail (d_row) cols c..c+3.
static __device__ __forceinline__ void hlift4(const float* __restrict__ row,
                                              int c, float4* s4, float4* d4) {
    const int fb = 2 * c - 4;          // 16-float window base (16B aligned)
    float w[16];
    if (fb >= 0 && fb + 15 <= 1023) {
        const float4* p = (const float4*)(row + fb);
        #pragma unroll
        for (int q = 0; q < 4; ++q) {
            float4 v = p[q];
            w[4*q+0] = v.x; w[4*q+1] = v.y; w[4*q+2] = v.z; w[4*q+3] = v.w;
        }
    } else {                           // image edge: clamped scalar loads
        #pragma unroll
        for (int t = 0; t < 16; ++t) {
            int gx = fb + t; gx = gx < 0 ? 0 : (gx > 1023 ? 1023 : gx);
            w[t] = row[gx];
        }
    }
    // window: E[c-2+i] = w[2i], O[c-2+i] = w[2i+1], i = 0..7
    // dd[t] = global d[c-1+t], t = 0..5
    float dd[6];
    #pragma unroll
    for (int t = 0; t < 6; ++t)
        dd[t] = w[2*t+3] - 0.5f * (w[2*t] + w[2*t+4]);
    // horizontal image-edge fixes (reflection collapses the stencil)
    if (c == 0)   { dd[1] = w[5]  - w[6]; dd[0] = dd[2]; }   // d[0]=O0-E1; d[-1]->d[1]
    if (c == 508) { dd[4] = w[11] - w[8]; dd[5] = dd[3]; }   // d[511]=O511-E510; d[512]->d[510]
    float ss[4];
    #pragma unroll
    for (int i = 0; i < 4; ++i)
        ss[i] = w[2*i+4] + 0.25f * (dd[i] + dd[i+2]);
    *s4 = make_float4(ss[0], ss[1], ss[2], ss[3]);
    *d4 = make_float4(dd[1], dd[2], dd[3], dd[4]);
}

__global__ __launch_bounds__(256) void ilwt53_v5(const float* __restrict__ x,
                                                 float* __restrict__ out) {
    const int tid = threadIdx.x;
    const int c0  = blockIdx.x * 32;   // half-res col origin (32 cols/block)
    const int r0  = blockIdx.y * 32;   // half-res row origin (32 rows/block)
    const int img = blockIdx.z;        // b*3 + ch

    const float* __restrict__ xim = x + (size_t)img * (1024 * 1024);

    const int rr = tid >> 3, ccg = tid & 7;
    const int r  = r0 + rr;
    const int c  = c0 + 4 * ccg;

    // Vertical stencil indices (half-res, reflected)
    const int k1 = mref(r - 1), k2 = mref(r + 1);
    const int ka = mref(k1 - 1), kd = mref(k2 + 1);
    // SE[m(k1+1)] == SE[r] except r==0 (-> SE[kd]); SE[m(k2-1)] == SE[r]
    // except r==511 (-> SE[ka]).  (Derivation: kb=m(k1+1), kc=m(k2-1).)

    // 8 full-res rows -> s,d fragments. 32 independent float4 loads total.
    float4 se_a, de_a, se_1, de_1, se_r, de_r, se_2, de_2, se_d, de_d;
    float4 so_1, do_1, so_r, do_r, so_2, do_2;
    hlift4(xim + (size_t)(2 * ka)     * 1024, c, &se_a, &de_a);
    hlift4(xim + (size_t)(2 * k1)     * 1024, c, &se_1, &de_1);
    hlift4(xim + (size_t)(2 * r )     * 1024, c, &se_r, &de_r);
    hlift4(xim + (size_t)(2 * k2)     * 1024, c, &se_2, &de_2);
    hlift4(xim + (size_t)(2 * kd)     * 1024, c, &se_d, &de_d);
    hlift4(xim + (size_t)(2 * k1 + 1) * 1024, c, &so_1, &do_1);
    hlift4(xim + (size_t)(2 * r  + 1) * 1024, c, &so_r, &do_r);
    hlift4(xim + (size_t)(2 * k2 + 1) * 1024, c, &so_2, &do_2);

    const float4 seB = (r == 0)   ? se_d : se_r;   // SE[m(k1+1)]
    const float4 seE = (r == 511) ? se_a : se_r;   // SE[m(k2-1)]
    const float4 deB = (r == 0)   ? de_d : de_r;
    const float4 deE = (r == 511) ? de_a : de_r;

    // L side: LH[m(r-1)], LH[r], LH[m(r+1)] -> LL, LH
    const float4 lh_m = lift_sub(so_1, se_a, seB);
    const float4 lh_c = lift_sub(so_r, se_1, se_2);
    const float4 lh_p = lift_sub(so_2, seE, se_d);
    const float4 ll   = lift_add(se_r, lh_m, lh_p);
    // H side: HH rows -> HL, HH
    const float4 hh_m = lift_sub(do_1, de_a, deB);
    const float4 hh_c = lift_sub(do_r, de_1, de_2);
    const float4 hh_p = lift_sub(do_2, deE, de_d);
    const float4 hl   = lift_add(de_r, hh_m, hh_p);

    const size_t plane = 512 * 512;
    float* __restrict__ ob = out + ((size_t)(img / 3) * 12 + (img % 3)) * plane;
    const size_t o = (size_t)r * 512 + c;
    *(float4*)(ob + o)             = ll;
    *(float4*)(ob + o + 3 * plane) = lh_c;
    *(float4*)(ob + o + 6 * plane) = hl;
    *(float4*)(ob + o + 9 * plane) = hh_c;
}

extern "C" void kernel_launch(void* const* d_in, const int* in_sizes, int n_in,
                              void* d_out, int out_size, void* d_ws, size_t ws_size,
                              hipStream_t stream) {
    const float* x = (const float*)d_in[0];
    float* out = (float*)d_out;
    dim3 grid(16, 16, 24);   // 16x16 half-res tiles per image, 24 images
    dim3 block(256);
    hipLaunchKernelGGL(ilwt53_v5, grid, block, 0, stream, x, out);
}

// Round 4
// 172.719 us; speedup vs baseline: 1.2108x; 1.2108x over previous
//
#include <hip/hip_runtime.h>

// 2D CDF 5/3 lifting wavelet, fused. Input x: (24,1024,1024) fp32.
// Output: (8,12,512,512) fp32, planes LL(0..2) LH(3..5) HL(6..8) HH(9..11).
//
// v6: COALESCED raw staging. v2/v4/v5 all load per-thread float4 windows at
// 32-64B lane stride -> one wave load touches ~64 cache lines using 16B of
// each (~4x TA line-request amplification, ~17us/CU of serialized L1 tag
// traffic in v2). Here:
//   A0: raw 71x18-float4 tile staged global->LDS with lane-consecutive
//       float4s (fully coalesced, ~6x fewer line requests).
//   A1: horizontal lifting reads its 24-float window from LDS (stride 76
//       floats = 12 mod 32 bank stagger), writes s/d to second LDS buffer.
//   B:  v4's verified merged vertical pass (single pass, no B1 phase).
// Two barriers. LDS 43KB -> 3 blocks/CU = 12 waves/CU, which equals what v2
// MEASURED at 37.6% occupancy; occupancy is established non-lever (v2-v5).

static __device__ __forceinline__ int mref(int k) {
    // _rpad reflect in half-res index space (N=512): e[-1]->E[1], e[512]->E[510]
    return k < 0 ? 1 : (k > 511 ? 510 : k);
}

static __device__ __forceinline__ float4 lift_sub(float4 o, float4 em, float4 ep) {
    float4 r;
    r.x = o.x - 0.5f * (em.x + ep.x);
    r.y = o.y - 0.5f * (em.y + ep.y);
    r.z = o.z - 0.5f * (em.z + ep.z);
    r.w = o.w - 0.5f * (em.w + ep.w);
    return r;
}

static __device__ __forceinline__ float4 lift_add(float4 e, float4 dm, float4 dp) {
    float4 r;
    r.x = e.x + 0.25f * (dm.x + dp.x);
    r.y = e.y + 0.25f * (dm.y + dp.y);
    r.z = e.z + 0.25f * (dm.z + dp.z);
    r.w = e.w + 0.25f * (dm.w + dp.w);
    return r;
}

#define RSTRIDE 19   // float4 per LDS row = 76 floats; 76 mod 32 = 12 bank stagger

__global__ __launch_bounds__(256) void ilwt53_v6(const float* __restrict__ x,
                                                 float* __restrict__ out) {
    const int tid = threadIdx.x;
    const int c0  = blockIdx.x * 32;   // half-res col origin
    const int r0  = blockIdx.y * 32;   // half-res row origin
    const int img = blockIdx.z;        // b*3 + ch
    const int rb  = 2 * r0 - 4;        // full-res row base (4-row halo)

    // raw tile: full-res rows rb..rb+70, full-res cols 2*c0-4 .. 2*c0+67
    __shared__ float4 raw4[71 * RSTRIDE];
    // s/d: s (smooth) at f4 index 0..7, d (detail) at f4 index 9..16
    __shared__ float4 sd4 [71 * RSTRIDE];

    const float* __restrict__ xim = x + (size_t)img * (1024 * 1024);

    // ---- Phase A0: coalesced stage, 71 rows x 18 float4 = 1278 items ----
    {
        float4 v[5];
        int    dst[5];
        bool   act[5];
        #pragma unroll
        for (int it = 0; it < 5; ++it) {
            int idx = tid + it * 256;
            act[it] = idx < 71 * 18;
            if (act[it]) {
                int rw = idx / 18;           // magic-mul division
                int q  = idx - rw * 18;
                dst[it] = rw * RSTRIDE + q;
                int gy = rb + rw; gy = gy < 0 ? 0 : (gy > 1023 ? 1023 : gy);
                const float* rp = xim + (size_t)gy * 1024;
                int fb = 2 * c0 - 4 + 4 * q;           // float index, 16B aligned
                if (fb >= 0 && fb + 3 <= 1023) {
                    v[it] = *(const float4*)(rp + fb);
                } else {                                // image edge: clamp
                    float a[4];
                    #pragma unroll
                    for (int e = 0; e < 4; ++e) {
                        int gx = fb + e; gx = gx < 0 ? 0 : (gx > 1023 ? 1023 : gx);
                        a[e] = rp[gx];
                    }
                    v[it] = make_float4(a[0], a[1], a[2], a[3]);
                }
            }
        }
        #pragma unroll
        for (int it = 0; it < 5; ++it)
            if (act[it]) raw4[dst[it]] = v[it];
    }
    __syncthreads();

    // ---- Phase A1: horizontal lifting from LDS windows ----
    // 71 rows x 4 col-groups = 284 items; item owns half-res cols c..c+7.
    #pragma unroll
    for (int it = 0; it < 2; ++it) {
        int i = tid + it * 256;
        if (i < 284) {
            int lr = i >> 2, g = i & 3;
            const float4* wr = raw4 + lr * RSTRIDE + 4 * g;
            float w[24];
            #pragma unroll
            for (int q = 0; q < 6; ++q) {
                float4 t = wr[q];
                w[4*q] = t.x; w[4*q+1] = t.y; w[4*q+2] = t.z; w[4*q+3] = t.w;
            }
            int c = c0 + 8 * g;
            // window: E[c-2+u] = w[2u], O[c-2+u] = w[2u+1], u = 0..11
            float d[10];
            #pragma unroll
            for (int t = 0; t < 10; ++t)
                d[t] = w[2*t+3] - 0.5f * (w[2*t] + w[2*t+4]);
            if (c == 0)   d[1] = w[5]  - w[6];    // global j=0
            if (c == 504) d[8] = w[19] - w[16];   // global j=511
            float s[8];
            #pragma unroll
            for (int i2 = 0; i2 < 8; ++i2)
                s[i2] = w[2*i2+4] + 0.25f * (d[i2] + d[i2+2]);
            if (c == 0)   s[0] = w[4]  + 0.5f * d[2];
            if (c == 504) s[7] = w[18] + 0.5f * d[7];

            float4* ps = sd4 + lr * RSTRIDE + 2 * g;
            ps[0] = make_float4(s[0], s[1], s[2], s[3]);
            ps[1] = make_float4(s[4], s[5], s[6], s[7]);
            float4* pd = sd4 + lr * RSTRIDE + 9 + 2 * g;
            pd[0] = make_float4(d[1], d[2], d[3], d[4]);
            pd[1] = make_float4(d[5], d[6], d[7], d[8]);
        }
    }
    __syncthreads();

    // ---- Phase B: merged vertical pass (v4 verified math) ----
    {
        const int rr = tid >> 3, ccg = tid & 7;
        const int r  = r0 + rr;
        const int k1 = mref(r - 1), k2 = mref(r + 1);
        const int ka = mref(k1 - 1), kb = mref(k1 + 1);
        const int kc = mref(k2 - 1), kd = mref(k2 + 1);

        // local LDS row of SE[k]/DE[k] is 2*(k-r0)+4, of SO[k]/DO[k] is +5;
        // all k above fall in [r0-2, r0+33] -> rows 0..70.
        #define SE_(k) (sd4[(2 * ((k) - r0) + 4) * RSTRIDE + ccg])
        #define SO_(k) (sd4[(2 * ((k) - r0) + 5) * RSTRIDE + ccg])
        #define DE_(k) (sd4[(2 * ((k) - r0) + 4) * RSTRIDE + 9 + ccg])
        #define DO_(k) (sd4[(2 * ((k) - r0) + 5) * RSTRIDE + 9 + ccg])

        const size_t plane = 512 * 512;
        float* __restrict__ ob = out + ((size_t)(img / 3) * 12 + (img % 3)) * plane;
        const size_t o = (size_t)r * 512 + c0 + 4 * ccg;

        // L side
        {
            float4 se_r  = SE_(r);
            float4 se_k1 = SE_(k1);
            float4 se_k2 = SE_(k2);
            float4 se_a  = SE_(ka);
            float4 se_b  = SE_(kb);
            float4 se_c  = SE_(kc);
            float4 se_d  = SE_(kd);
            float4 so_r  = SO_(r);
            float4 so_k1 = SO_(k1);
            float4 so_k2 = SO_(k2);

            float4 lh_c = lift_sub(so_r,  se_k1, se_k2);   // LH[r]
            float4 lh_m = lift_sub(so_k1, se_a,  se_b);    // LH[m(r-1)]
            float4 lh_p = lift_sub(so_k2, se_c,  se_d);    // LH[m(r+1)]
            float4 ll   = lift_add(se_r, lh_m, lh_p);

            *(float4*)(ob + o)             = ll;           // LL plane
            *(float4*)(ob + o + 3 * plane) = lh_c;         // LH plane
        }
        // H side
        {
            float4 de_r  = DE_(r);
            float4 de_k1 = DE_(k1);
            float4 de_k2 = DE_(k2);
            float4 de_a  = DE_(ka);
            float4 de_b  = DE_(kb);
            float4 de_c  = DE_(kc);
            float4 de_d  = DE_(kd);
            float4 do_r  = DO_(r);
            float4 do_k1 = DO_(k1);
            float4 do_k2 = DO_(k2);

            float4 hh_c = lift_sub(do_r,  de_k1, de_k2);   // HH[r]
            float4 hh_m = lift_sub(do_k1, de_a,  de_b);    // HH[m(r-1)]
            float4 hh_p = lift_sub(do_k2, de_c,  de_d);    // HH[m(r+1)]
            float4 hl   = lift_add(de_r, hh_m, hh_p);

            *(float4*)(ob + o + 6 * plane) = hl;           // HL plane
            *(float4*)(ob + o + 9 * plane) = hh_c;         // HH plane
        }
        #undef SE_
        #undef SO_
        #undef DE_
        #undef DO_
    }
}

extern "C" void kernel_launch(void* const* d_in, const int* in_sizes, int n_in,
                              void* d_out, int out_size, void* d_ws, size_t ws_size,
                              hipStream_t stream) {
    const float* x = (const float*)d_in[0];
    float* out = (float*)d_out;
    dim3 grid(16, 16, 24);   // 16x16 half-res tiles per image, 24 images
    dim3 block(256);
    hipLaunchKernelGGL(ilwt53_v6, grid, block, 0, stream, x, out);
}